// Round 13
// baseline (812.732 us; speedup 1.0000x reference)
//
#include <hip/hip_runtime.h>

typedef _Float16 f16x8 __attribute__((ext_vector_type(8)));
typedef _Float16 f16x4 __attribute__((ext_vector_type(4)));
typedef float    f32x4 __attribute__((ext_vector_type(4)));
typedef float    f32x16 __attribute__((ext_vector_type(16)));

#define BM 128
#define BN 128
#define BK 32

// async global->LDS, 16B per lane. LDS dst must be wave-uniform base + lane*16.
__device__ __forceinline__ void gld16(const void* g, void* l) {
  __builtin_amdgcn_global_load_lds(
      (__attribute__((address_space(1))) void*)const_cast<void*>(g),
      (__attribute__((address_space(3))) void*)l, 16, 0, 0);
}

// Branchless activations from ONE native exp.
__device__ __forceinline__ float act_clip(int f, float v, float cap) {
  const float sc = 1.0507009873554805f, al = 1.6732632423543772f;
  const float av = fabsf(v);
  const float e  = __expf(-av);
  const float e2 = e * e;
  const bool  pos = (v >= 0.0f);

  const float r1 = __builtin_amdgcn_rcpf(1.0f + e);
  const float sig = pos ? r1 : e * r1;                 // sigmoid(v)
  float th = (1.0f - e2) * __builtin_amdgcn_rcpf(1.0f + e2);
  th = pos ? th : -th;                                  // tanh(v)
  const float rel = fmaxf(v, 0.0f);
  const float lk  = pos ? v : 0.1f * v;
  const float sel = pos ? sc * v : sc * al * (e - 1.0f);

  float out = rel;
  out = (f == 1) ? sig : out;
  out = (f == 2) ? th  : out;
  out = (f == 3) ? lk  : out;
  out = (f == 4) ? sel : out;
  return fminf(out, cap);
}

// C[M,N] = A[M,K] @ W[N,K]^T + bias, then per-column activation+clip.
// Split-f16 GEMM; products: Ah*Wh always, +Ah*Wl if WLO, +Al*Wh if ALO.
//
// MEASURED LAWS on this problem (R0..R12):
//  - HOT LOOP STRUCTURE CLOSED: blocks/CU {4,2,1} -> {155,174,180} us;
//    occupancy-neutral prefetch regresses via broken write-line assembly
//    (R8). Keep 2-barrier / 32KB / 4-blocks; j-inner line-complete stores.
//  - ERROR MODEL (4-point: R2/R9/R11/R12): per-drop eps~0.025, gain G~5;
//    drop with g GEMMs downstream adds ~eps*G^g. g<=1 double-drops = +0.18
//    (0.25->0.426, R12). g=2 blows budget (R11: 1.77). Ladder FULLY SPENT.
//  - LDS swizzle (f16 64B rows, both-sides XOR): conflicts 8.4M -> 0.
//  - Don't fuse fp32 staging into the GEMM (R7).
//
// R13: MFMA shape 16x16x32 -> 32x32x16 at identical tile/schedule.
// 24 MFMA x 8.07cyc vs 48 x 4.85cyc per wave-K-tile = -17% matrix-pipe
// cycles (ubench 2382 vs 2075 TF); halved MFMA issue slots. ds_read
// bytes/pattern unchanged (same 8-combo bank spread -> 0 conflicts).
// Input frags: row = lane&31, k-group = lane>>5 (8 contig k) — same rule
// as the session-verified 16x16 path. C/D (HW-verified m74/m101):
// col = lane&31, row = (reg&3) + 8*(reg>>2) + 4*(lane>>5).
//
// f16 swizzle: row = 64B = 4 x 16B chunks; staging loads GLOBAL chunk
// c ^ ((srow>>1)&3) into linear LDS chunk c; frag reads use chunk
// (kc*2 + kg) ^ ((ml32>>1)&3)  (wm/wn + i2*32 multiples of 32 -> row-XOR
// is lane-pure).
//
// 1D grid with XCD swizzle: id = xcd + 8*(c + nCol*g), r = 8g+xcd.
template<bool ALO, bool WLO>
__global__ __launch_bounds__(256, 4) void gemm_split_act(
    const _Float16* __restrict__ Ahi, const _Float16* __restrict__ Alo,
    const _Float16* __restrict__ Whi, const _Float16* __restrict__ Wlo,
    const float* __restrict__ bias, const int* __restrict__ fid,
    const float* __restrict__ cap, int N, int K, int nCol, int nRow,
    _Float16* __restrict__ Ohi, _Float16* __restrict__ Olo,
    float* __restrict__ Ofin)
{
  __shared__ _Float16 sA[2][BM * BK];   // [hi/lo][row*BK + k], rows = batch
  __shared__ _Float16 sB[2][BN * BK];   // [hi/lo][row*BK + k], rows = out-feature

  const int tid  = threadIdx.x;
  const int lane = tid & 63;
  const int wave = tid >> 6;
  const int wm = (wave >> 1) * 64;      // wave's row offset in 128x128 tile
  const int wn = (wave & 1) * 64;       // wave's col offset
  const int ml32 = lane & 31;
  const int kg   = lane >> 5;           // k-group (0/1): 8 contig k each
  const int sxr  = (ml32 >> 1) & 3;     // read-side row-XOR (lane-pure)

  int rb, cb;
  if ((nRow & 7) == 0) {
    const int id = blockIdx.x;
    const int xcd = id & 7, slot = id >> 3;
    cb = slot % nCol;
    rb = (slot / nCol) * 8 + xcd;
  } else {
    cb = blockIdx.x % nCol;
    rb = blockIdx.x / nCol;
  }

  const long row0 = (long)rb * BM;
  const int  col0 = cb * BN;

  // staging: thread covers global rows (tid>>2) and 64+(tid>>2), 16B chunk (tid&3).
  // Global chunk pre-swizzled; note ((srow+64)>>1)&3 == ((srow>>1)&3).
  const int srow = tid >> 2;
  const int sx   = (srow >> 1) & 3;
  const int scol = ((tid & 3) ^ sx) * 8;          // f16 elements
  const _Float16* gAh = Ahi + (row0 + srow) * (long)K + scol;
  const _Float16* gAl = ALO ? Alo + (row0 + srow) * (long)K + scol : nullptr;
  const _Float16* gBh = Whi + (long)(col0 + srow) * K + scol;
  const _Float16* gBl = WLO ? Wlo + (long)(col0 + srow) * K + scol : nullptr;

  f32x16 acc[2][2] = {};                 // [i2 rowblk][j2 colblk], 32x32 each

  for (int k0 = 0; k0 < K; k0 += BK) {
    gld16(gAh + k0,                &sA[0][tid * 8]);
    gld16(gAh + (long)64 * K + k0, &sA[0][64 * BK + tid * 8]);
    if constexpr (ALO) {
      gld16(gAl + k0,                &sA[1][tid * 8]);
      gld16(gAl + (long)64 * K + k0, &sA[1][64 * BK + tid * 8]);
    }
    gld16(gBh + k0,                &sB[0][tid * 8]);
    gld16(gBh + (long)64 * K + k0, &sB[0][64 * BK + tid * 8]);
    if constexpr (WLO) {
      gld16(gBl + k0,                &sB[1][tid * 8]);
      gld16(gBl + (long)64 * K + k0, &sB[1][64 * BK + tid * 8]);
    }
    __syncthreads();   // drains vmcnt: staging complete

    // two k-chunks of 16 per LDS tile; frags loaded per-kc to cap registers
#pragma unroll
    for (int kc = 0; kc < 2; ++kc) {
      const int cxk = ((kc * 2 + kg) ^ sxr) * 8;  // swizzled 16B chunk
      const int ar0 = (wm +      ml32) * BK + cxk;
      const int ar1 = (wm + 32 + ml32) * BK + cxk;
      const int br0 = (wn +      ml32) * BK + cxk;
      const int br1 = (wn + 32 + ml32) * BK + cxk;

      f16x8 ah0 = *(const f16x8*)&sA[0][ar0];
      f16x8 ah1 = *(const f16x8*)&sA[0][ar1];
      f16x8 bh0 = *(const f16x8*)&sB[0][br0];
      f16x8 bh1 = *(const f16x8*)&sB[0][br1];
      acc[0][0] = __builtin_amdgcn_mfma_f32_32x32x16_f16(ah0, bh0, acc[0][0], 0, 0, 0);
      acc[0][1] = __builtin_amdgcn_mfma_f32_32x32x16_f16(ah0, bh1, acc[0][1], 0, 0, 0);
      acc[1][0] = __builtin_amdgcn_mfma_f32_32x32x16_f16(ah1, bh0, acc[1][0], 0, 0, 0);
      acc[1][1] = __builtin_amdgcn_mfma_f32_32x32x16_f16(ah1, bh1, acc[1][1], 0, 0, 0);

      if constexpr (WLO) {
        f16x8 bl0 = *(const f16x8*)&sB[1][br0];
        f16x8 bl1 = *(const f16x8*)&sB[1][br1];
        acc[0][0] = __builtin_amdgcn_mfma_f32_32x32x16_f16(ah0, bl0, acc[0][0], 0, 0, 0);
        acc[0][1] = __builtin_amdgcn_mfma_f32_32x32x16_f16(ah0, bl1, acc[0][1], 0, 0, 0);
        acc[1][0] = __builtin_amdgcn_mfma_f32_32x32x16_f16(ah1, bl0, acc[1][0], 0, 0, 0);
        acc[1][1] = __builtin_amdgcn_mfma_f32_32x32x16_f16(ah1, bl1, acc[1][1], 0, 0, 0);
      }
      if constexpr (ALO) {
        f16x8 al0 = *(const f16x8*)&sA[1][ar0];
        f16x8 al1 = *(const f16x8*)&sA[1][ar1];
        acc[0][0] = __builtin_amdgcn_mfma_f32_32x32x16_f16(al0, bh0, acc[0][0], 0, 0, 0);
        acc[0][1] = __builtin_amdgcn_mfma_f32_32x32x16_f16(al0, bh1, acc[0][1], 0, 0, 0);
        acc[1][0] = __builtin_amdgcn_mfma_f32_32x32x16_f16(al1, bh0, acc[1][0], 0, 0, 0);
        acc[1][1] = __builtin_amdgcn_mfma_f32_32x32x16_f16(al1, bh1, acc[1][1], 0, 0, 0);
      }
    }
    __syncthreads();   // all frag reads done before next staging overwrites
  }

  // epilogue: 32x32 C/D layout col = lane&31, row = (reg&3)+8*(reg>>2)+4*kg.
  // Each store: 32 lanes x 2B contiguous = one complete 64B line per row-half
  // (line-complete by construction — the R9 write-assembly win, strengthened).
  float bj[2], cj[2];
  int   fj[2];
#pragma unroll
  for (int j2 = 0; j2 < 2; ++j2) {
    const int col = col0 + wn + j2 * 32 + ml32;
    bj[j2] = bias[col];
    fj[j2] = fid[col];
    cj[j2] = cap[col];
  }
  const long colbase = col0 + wn + ml32;
#pragma unroll
  for (int i2 = 0; i2 < 2; ++i2) {
#pragma unroll
    for (int r = 0; r < 16; ++r) {
      const long row = row0 + wm + i2 * 32 + (r & 3) + 8 * (r >> 2) + 4 * kg;
      const long rowoff = row * (long)N + colbase;
#pragma unroll
      for (int j2 = 0; j2 < 2; ++j2) {
        float v = act_clip(fj[j2], acc[i2][j2][r] + bj[j2], cj[j2]);
        const long idx = rowoff + j2 * 32;
        if (Ofin) {
          Ofin[idx] = v;
        } else {
          _Float16 h = (_Float16)v;
          Ohi[idx] = h;
          if (Olo) Olo[idx] = (_Float16)(v - (float)h);
        }
      }
    }
  }
}

// fp32 -> (hi,lo) f16 split planes, 4 elems/thread
__global__ void split_f32(const float* __restrict__ x, _Float16* __restrict__ hi,
                          _Float16* __restrict__ lo, long n)
{
  long i = ((long)blockIdx.x * 256 + threadIdx.x) * 4;
  if (i >= n) return;
  float4 v = *(const float4*)(x + i);
  f16x4 h, l;
  h[0] = (_Float16)v.x; l[0] = (_Float16)(v.x - (float)h[0]);
  h[1] = (_Float16)v.y; l[1] = (_Float16)(v.y - (float)h[1]);
  h[2] = (_Float16)v.z; l[2] = (_Float16)(v.z - (float)h[2]);
  h[3] = (_Float16)v.w; l[3] = (_Float16)(v.w - (float)h[3]);
  *(f16x4*)(hi + i) = h;
  *(f16x4*)(lo + i) = l;
}

// fp32 -> (hi,lo) f16 split planes for the THREE weight tensors in one launch.
__global__ void split_weights(const float* __restrict__ w0,
                              const float* __restrict__ w1,
                              const float* __restrict__ w2,
                              long n0, long n1, long n2,
                              _Float16* __restrict__ hi, _Float16* __restrict__ lo)
{
  long i = ((long)blockIdx.x * 256 + threadIdx.x) * 4;
  if (i >= n0 + n1 + n2) return;
  const float* src;
  long off;
  if (i < n0)            { src = w0; off = i; }
  else if (i < n0 + n1)  { src = w1; off = i - n0; }
  else                   { src = w2; off = i - n0 - n1; }
  float4 v = *(const float4*)(src + off);
  f16x4 h, l;
  h[0] = (_Float16)v.x; l[0] = (_Float16)(v.x - (float)h[0]);
  h[1] = (_Float16)v.y; l[1] = (_Float16)(v.y - (float)h[1]);
  h[2] = (_Float16)v.z; l[2] = (_Float16)(v.z - (float)h[2]);
  h[3] = (_Float16)v.w; l[3] = (_Float16)(v.w - (float)h[3]);
  *(f16x4*)(hi + i) = h;
  *(f16x4*)(lo + i) = l;
}

extern "C" void kernel_launch(void* const* d_in, const int* in_sizes, int n_in,
                              void* d_out, int out_size, void* d_ws, size_t ws_size,
                              hipStream_t stream)
{
  const float* input = (const float*)d_in[0];
  const float* W_in  = (const float*)d_in[1];
  const float* b_in  = (const float*)d_in[2];
  const float* W_h   = (const float*)d_in[3];
  const float* b_h   = (const float*)d_in[4];
  const float* W_out = (const float*)d_in[5];
  const float* b_out = (const float*)d_in[6];
  const float* m_in  = (const float*)d_in[7];
  const float* m_h   = (const float*)d_in[8];
  const float* m_out = (const float*)d_in[9];
  const int* fid_in  = (const int*)d_in[10];
  const int* fid_h   = (const int*)d_in[11];
  const int* fid_out = (const int*)d_in[12];

  const int X     = in_sizes[2];                 // 512
  const int D_IN  = in_sizes[1] / X;             // 512
  const int Z     = in_sizes[3] / (X * X);       // 4
  const int D_OUT = in_sizes[6];                 // 128
  const long B    = (long)in_sizes[0] / D_IN;    // 65536

  const long w_elems = (long)X * D_IN + (long)Z * X * X + (long)D_OUT * X;
  _Float16* Whi = (_Float16*)d_ws;
  _Float16* Wlo = Whi + w_elems;
  char* actbase = (char*)(Wlo + w_elems);

  // row chunking so 2 ping-pong activation buffers (hi+lo f16 each) fit in ws
  size_t wbytes = 4 * (size_t)w_elems;
  size_t avail  = ws_size > wbytes ? ws_size - wbytes : 0;
  long R = (long)(avail / (8 * (size_t)X));
  R = (R / BM) * BM;
  if (R > B) R = B;
  if (R < BM) R = BM;

  _Float16* bufhi[2];
  _Float16* buflo[2];
  bufhi[0] = (_Float16*)actbase;
  buflo[0] = bufhi[0] + R * (long)X;
  bufhi[1] = buflo[0] + R * (long)X;
  buflo[1] = bufhi[1] + R * (long)X;

  // split all weights in ONE launch
  {
    long n0 = (long)X * D_IN;
    long n1 = (long)Z * X * X;
    long n2 = (long)D_OUT * X;
    long tot = n0 + n1 + n2;
    split_weights<<<(int)((tot / 4 + 255) / 256), 256, 0, stream>>>(
        W_in, W_h, W_out, n0, n1, n2, Whi, Wlo);
  }

  const long woff_h   = (long)X * D_IN;
  const long woff_out = woff_h + (long)Z * X * X;

  for (long r0 = 0; r0 < B; r0 += R) {
    const long rows = (B - r0 < R) ? (B - r0) : R;

    // input chunk -> split planes (lo load-bearing at g=5, R2)
    {
      long n = rows * (long)D_IN;
      split_f32<<<(int)((n / 4 + 255) / 256), 256, 0, stream>>>(input + r0 * D_IN, bufhi[0], buflo[0], n);
    }

    const int nRow  = (int)(rows / BM);
    const int nColH = X / BN;
    dim3 gridH((unsigned)(nRow * nColH));
    // GEMM chain: L0, h1(i=0), h2(i=1), h3(i=2), h4(i=3), out.
    // Precision schedule (R12-validated, absmax 0.426 vs 1.03):
    //   L0 (g=5), h1 (g=4), h2 (g=3), h3 (g=2): full 3-product.
    //   h3 output lo NOT written; h4 (g=1): 1-product <f,f>.
    //   out (g=0): 1-product <f,f>.
    gemm_split_act<true, true><<<gridH, 256, 0, stream>>>(bufhi[0], buflo[0], Whi, Wlo,
        b_in, fid_in, m_in, X, D_IN, nColH, nRow, bufhi[1], buflo[1], nullptr);
    int cur = 1;
    for (int i = 0; i < Z; i++) {
      const _Float16* wh = Whi + woff_h + (long)i * X * X;
      const _Float16* wl = Wlo + woff_h + (long)i * X * X;
      if (i < Z - 1) {
        // full precision; last full layer (h3, i==Z-2) writes hi only
        _Float16* olo = (i == Z - 2) ? nullptr : buflo[1 - cur];
        gemm_split_act<true, true><<<gridH, 256, 0, stream>>>(bufhi[cur], buflo[cur], wh, wl,
            b_h + (long)i * X, fid_h + (long)i * X, m_h + (long)i * X, X, X,
            nColH, nRow, bufhi[1 - cur], olo, nullptr);
      } else {
        // h4: 1-product
        gemm_split_act<false, false><<<gridH, 256, 0, stream>>>(bufhi[cur], nullptr, wh, nullptr,
            b_h + (long)i * X, fid_h + (long)i * X, m_h + (long)i * X, X, X,
            nColH, nRow, bufhi[1 - cur], nullptr, nullptr);
      }
      cur ^= 1;
    }
    const int nColO = D_OUT / BN;
    dim3 gridO((unsigned)(nRow * nColO));
    gemm_split_act<false, false><<<gridO, 256, 0, stream>>>(bufhi[cur], nullptr,
        Whi + woff_out, nullptr, b_out, fid_out, m_out, D_OUT, X,
        nColO, nRow, nullptr, nullptr, (float*)d_out + r0 * (long)D_OUT);
  }
}